// Round 7
// baseline (975.833 us; speedup 1.0000x reference)
//
#include <hip/hip_runtime.h>

// ---------------- CSR construction ----------------

__global__ void count_kernel(const int* __restrict__ dst, int* __restrict__ counts, int E) {
    int e = blockIdx.x * 256 + threadIdx.x;
    if (e < E) atomicAdd(&counts[dst[e]], 1);
}

__global__ void scan_local(const int* __restrict__ counts, int* __restrict__ rowptr,
                           int* __restrict__ bsums, float* __restrict__ dinv, int N) {
    __shared__ int sm[256];
    int t = threadIdx.x;
    int gid = blockIdx.x * 256 + t;
    int v = (gid < N) ? counts[gid] : 0;
    if (gid < N) dinv[gid] = rsqrtf((float)v + 1.0f);
    int x = v;
    sm[t] = x; __syncthreads();
    for (int off = 1; off < 256; off <<= 1) {
        int y = (t >= off) ? sm[t - off] : 0;
        __syncthreads();
        x += y; sm[t] = x; __syncthreads();
    }
    if (gid < N) rowptr[gid] = x - v;
    if (t == 255) bsums[blockIdx.x] = x;
}

__global__ void scan_bsums(int* bsums, int nb) {
    __shared__ int sm[512];
    int t = threadIdx.x;
    int v = (t < nb) ? bsums[t] : 0;
    int x = v;
    sm[t] = x; __syncthreads();
    for (int off = 1; off < 512; off <<= 1) {
        int y = (t >= off) ? sm[t - off] : 0;
        __syncthreads();
        x += y; sm[t] = x; __syncthreads();
    }
    if (t < nb) bsums[t] = x - v;
}

__global__ void scan_add(int* __restrict__ rowptr, const int* __restrict__ bsums, int N) {
    int gid = blockIdx.x * 256 + threadIdx.x;
    if (gid < N) rowptr[gid] += bsums[blockIdx.x];
}

__global__ void fill_kernel(const int* __restrict__ src, const int* __restrict__ dst,
                            const int* __restrict__ rowptr, int* __restrict__ fillc,
                            const float* __restrict__ dinv,
                            int* __restrict__ csr, float* __restrict__ csrw, int E) {
    int e = blockIdx.x * 256 + threadIdx.x;
    if (e < E) {
        int d = dst[e];
        int s = src[e];
        int pos = rowptr[d] + atomicAdd(&fillc[d], 1);
        csr[pos] = s;
        csrw[pos] = dinv[s];
    }
}

// Unrolled shuffle-gather: 8 outstanding row-gathers, 4 independent acc chains.
// Indices stay register-resident (shfl), so loads pipeline without scalar-mem deps.
#define AGG_GATHER(M, a0, a1, a2, a3)                                        \
    for (int base = 0; base < cnt; base += 64) {                             \
        int nb = min(64, cnt - base);                                        \
        int idx = 0; float ds = 0.f;                                         \
        if (lane < nb) {                                                     \
            idx = csr[start + base + lane];                                  \
            ds  = csrw[start + base + lane];                                 \
        }                                                                    \
        int j = 0;                                                           \
        for (; j + 8 <= nb; j += 8) {                                        \
            int   s0 = __shfl(idx, j + 0), s1 = __shfl(idx, j + 1);          \
            int   s2 = __shfl(idx, j + 2), s3 = __shfl(idx, j + 3);          \
            int   s4 = __shfl(idx, j + 4), s5 = __shfl(idx, j + 5);          \
            int   s6 = __shfl(idx, j + 6), s7 = __shfl(idx, j + 7);          \
            float d0 = __shfl(ds, j + 0),  d1 = __shfl(ds, j + 1);           \
            float d2 = __shfl(ds, j + 2),  d3 = __shfl(ds, j + 3);           \
            float d4 = __shfl(ds, j + 4),  d5 = __shfl(ds, j + 5);           \
            float d6 = __shfl(ds, j + 6),  d7 = __shfl(ds, j + 7);           \
            float g0 = M[(size_t)s0 * 64 + lane];                            \
            float g1 = M[(size_t)s1 * 64 + lane];                            \
            float g2 = M[(size_t)s2 * 64 + lane];                            \
            float g3 = M[(size_t)s3 * 64 + lane];                            \
            float g4 = M[(size_t)s4 * 64 + lane];                            \
            float g5 = M[(size_t)s5 * 64 + lane];                            \
            float g6 = M[(size_t)s6 * 64 + lane];                            \
            float g7 = M[(size_t)s7 * 64 + lane];                            \
            a0 = fmaf(d0, g0, a0); a1 = fmaf(d1, g1, a1);                    \
            a2 = fmaf(d2, g2, a2); a3 = fmaf(d3, g3, a3);                    \
            a0 = fmaf(d4, g4, a0); a1 = fmaf(d5, g5, a1);                    \
            a2 = fmaf(d6, g6, a2); a3 = fmaf(d7, g7, a3);                    \
        }                                                                    \
        for (; j < nb; ++j) {                                                \
            int s = __shfl(idx, j); float d = __shfl(ds, j);                 \
            a0 = fmaf(d, M[(size_t)s * 64 + lane], a0);                      \
        }                                                                    \
    }

// ------- layer 1, NO separate gemm:  Y = (relu(agg(X)@W1 + b1)) @ W2 -------
// Uses agg(X@W1) == agg(X)@W1 (aggregation is linear). Same gather traffic as
// gathering XW, but the standalone gemm64 dispatch + xw round-trip disappear.

__global__ void agg_layer1_kernel(const float* __restrict__ X, const int* __restrict__ csr,
                                  const float* __restrict__ csrw,
                                  const int* __restrict__ rowptr, const int* __restrict__ counts,
                                  const float* __restrict__ dinv, const float* __restrict__ W1,
                                  const float* __restrict__ b1, const float* __restrict__ W2,
                                  float* __restrict__ Y, int N) {
    __shared__ float W1l[64 * 64];
    __shared__ float W2l[64 * 64];
    int tid = threadIdx.x;
    for (int i = tid; i < 4096; i += 512) { W1l[i] = W1[i]; W2l[i] = W2[i]; }
    __syncthreads();
    int lane = tid & 63, wave = tid >> 6;
    float bb = b1[lane];
    int v0 = blockIdx.x * 8 + wave;
    int stride = gridDim.x * 8;
    for (int v = v0; v < N; v += stride) {
        int start = rowptr[v], cnt = counts[v];
        float dv = dinv[v];
        float a0 = dv * X[(size_t)v * 64 + lane], a1 = 0.f, a2 = 0.f, a3 = 0.f;
        AGG_GATHER(X, a0, a1, a2, a3)
        float z = dv * ((a0 + a1) + (a2 + a3));   // z = agg(X) row, lane = feature
        float h = bb;                              // h1 = relu(z @ W1 + b1)
#pragma unroll
        for (int k = 0; k < 64; ++k)
            h = fmaf(__shfl(z, k), W1l[k * 64 + lane], h);
        h = fmaxf(h, 0.f);
        float y = 0.f;                             // Y = h1 @ W2
#pragma unroll
        for (int k = 0; k < 64; ++k)
            y = fmaf(__shfl(h, k), W2l[k * 64 + lane], y);
        Y[(size_t)v * 64 + lane] = y;
    }
}

// ------- layer2 agg fused with MLP head -------

__global__ void agg_head_kernel(const float* __restrict__ Yin, const int* __restrict__ csr,
                                const float* __restrict__ csrw,
                                const int* __restrict__ rowptr, const int* __restrict__ counts,
                                const float* __restrict__ dinv, const float* __restrict__ b2,
                                const float* __restrict__ dW1, const float* __restrict__ db1,
                                const float* __restrict__ dW2, const float* __restrict__ db2,
                                float* __restrict__ out, int N) {
    __shared__ float D1[64 * 64];
    int tid = threadIdx.x;
    for (int i = tid; i < 4096; i += 256) D1[i] = dW1[i];
    __syncthreads();
    int lane = tid & 63, wave = tid >> 6;
    int c = lane & 15, part = lane >> 4;
    float d2r[16];
#pragma unroll
    for (int kk = 0; kk < 16; ++kk) d2r[kk] = dW2[(part * 16 + kk) * 16 + c];
    float bbl = b2[lane];
    float bb1 = db1[lane];
    float ob  = db2[c];
    int v0 = blockIdx.x * 4 + wave;
    int stride = gridDim.x * 4;
    for (int v = v0; v < N; v += stride) {
        int start = rowptr[v], cnt = counts[v];
        float dv = dinv[v];
        float a0 = dv * Yin[(size_t)v * 64 + lane], a1 = 0.f, a2 = 0.f, a3 = 0.f;
        AGG_GATHER(Yin, a0, a1, a2, a3)
        float h2 = fmaxf(fmaf(dv, (a0 + a1) + (a2 + a3), bbl), 0.f);  // relu(agg + b2)
        float a = bb1;
#pragma unroll
        for (int k = 0; k < 64; ++k)
            a = fmaf(__shfl(h2, k), D1[k * 64 + lane], a);
        a = fmaxf(a, 0.f);
        float o = 0.f;
#pragma unroll
        for (int kk = 0; kk < 16; ++kk)
            o = fmaf(__shfl(a, part * 16 + kk), d2r[kk], o);
        o += __shfl_xor(o, 16);
        o += __shfl_xor(o, 32);
        if (lane < 16) out[(size_t)v * 16 + lane] = o + ob;
    }
}

// ---------------- launch ----------------

extern "C" void kernel_launch(void* const* d_in, const int* in_sizes, int n_in,
                              void* d_out, int out_size, void* d_ws, size_t ws_size,
                              hipStream_t stream) {
    const float* x   = (const float*)d_in[0];
    const int*   ei  = (const int*)d_in[1];
    const float* W1  = (const float*)d_in[2];
    const float* b1  = (const float*)d_in[3];
    const float* W2  = (const float*)d_in[4];
    const float* b2  = (const float*)d_in[5];
    const float* dW1 = (const float*)d_in[6];
    const float* db1 = (const float*)d_in[7];
    const float* dW2 = (const float*)d_in[8];
    const float* db2 = (const float*)d_in[9];
    float* out = (float*)d_out;

    int N = in_sizes[0] / 64;
    int E = in_sizes[1] / 2;
    const int* src = ei;
    const int* dst = ei + E;

    size_t off = 0;
    auto alloc = [&](size_t bytes) {
        void* p = (char*)d_ws + off;
        off += (bytes + 511) & ~(size_t)511;
        return p;
    };
    int*   counts = (int*)alloc((size_t)N * 4);
    int*   fillc  = (int*)alloc((size_t)N * 4);
    int*   rowptr = (int*)alloc((size_t)N * 4);
    int*   bsums  = (int*)alloc(512 * 4);
    int*   csr    = (int*)alloc((size_t)E * 4);
    float* csrw   = (float*)alloc((size_t)E * 4);
    float* dinv   = (float*)alloc((size_t)N * 4);
    float* yw     = (float*)alloc((size_t)N * 64 * 4);

    hipMemsetAsync(counts, 0, (size_t)N * 4, stream);
    hipMemsetAsync(fillc, 0, (size_t)N * 4, stream);

    int nbN = (N + 255) / 256;
    int nbE = (E + 255) / 256;

    count_kernel<<<nbE, 256, 0, stream>>>(dst, counts, E);
    scan_local<<<nbN, 256, 0, stream>>>(counts, rowptr, bsums, dinv, N);
    scan_bsums<<<1, 512, 0, stream>>>(bsums, nbN);
    scan_add<<<nbN, 256, 0, stream>>>(rowptr, bsums, N);
    fill_kernel<<<nbE, 256, 0, stream>>>(src, dst, rowptr, fillc, dinv, csr, csrw, E);

    agg_layer1_kernel<<<2048, 512, 0, stream>>>(x, csr, csrw, rowptr, counts, dinv,
                                                W1, b1, W2, yw, N);
    agg_head_kernel<<<2048, 256, 0, stream>>>(yw, csr, csrw, rowptr, counts, dinv, b2,
                                              dW1, db1, dW2, db2, out, N);
}

// Round 8
// 923.285 us; speedup vs baseline: 1.0569x; 1.0569x over previous
//
#include <hip/hip_runtime.h>

// ---------------- CSR construction ----------------

__global__ void count_kernel(const int* __restrict__ dst, int* __restrict__ counts, int E) {
    int e = blockIdx.x * 256 + threadIdx.x;
    if (e < E) atomicAdd(&counts[dst[e]], 1);
}

__global__ void scan_local(const int* __restrict__ counts, int* __restrict__ rowptr,
                           int* __restrict__ bsums, float* __restrict__ dinv, int N) {
    __shared__ int sm[256];
    int t = threadIdx.x;
    int gid = blockIdx.x * 256 + t;
    int v = (gid < N) ? counts[gid] : 0;
    if (gid < N) dinv[gid] = rsqrtf((float)v + 1.0f);
    int x = v;
    sm[t] = x; __syncthreads();
    for (int off = 1; off < 256; off <<= 1) {
        int y = (t >= off) ? sm[t - off] : 0;
        __syncthreads();
        x += y; sm[t] = x; __syncthreads();
    }
    if (gid < N) rowptr[gid] = x - v;
    if (t == 255) bsums[blockIdx.x] = x;
}

__global__ void scan_bsums(int* bsums, int nb) {
    __shared__ int sm[512];
    int t = threadIdx.x;
    int v = (t < nb) ? bsums[t] : 0;
    int x = v;
    sm[t] = x; __syncthreads();
    for (int off = 1; off < 512; off <<= 1) {
        int y = (t >= off) ? sm[t - off] : 0;
        __syncthreads();
        x += y; sm[t] = x; __syncthreads();
    }
    if (t < nb) bsums[t] = x - v;
}

__global__ void scan_add(int* __restrict__ rowptr, const int* __restrict__ bsums, int N) {
    int gid = blockIdx.x * 256 + threadIdx.x;
    if (gid < N) rowptr[gid] += bsums[blockIdx.x];
}

__global__ void fill_kernel(const int* __restrict__ src, const int* __restrict__ dst,
                            const int* __restrict__ rowptr, int* __restrict__ fillc,
                            const float* __restrict__ dinv,
                            int* __restrict__ csr, float* __restrict__ csrw, int E) {
    int e = blockIdx.x * 256 + threadIdx.x;
    if (e < E) {
        int d = dst[e];
        int s = src[e];
        int pos = rowptr[d] + atomicAdd(&fillc[d], 1);
        csr[pos] = s;
        csrw[pos] = dinv[s];
    }
}

// 4-wide shuffle-gather: 4 independent gathers in flight, ~35 live VGPRs
// (R7's 8-wide needed >64 and spilled to scratch: WRITE_SIZE 361MB vs 26MB output).
#define AGG_GATHER4(M, a0, a1, a2, a3)                                       \
    for (int base = 0; base < cnt; base += 64) {                             \
        int nb = min(64, cnt - base);                                        \
        int idx = 0; float ds = 0.f;                                         \
        if (lane < nb) {                                                     \
            idx = csr[start + base + lane];                                  \
            ds  = csrw[start + base + lane];                                 \
        }                                                                    \
        int j = 0;                                                           \
        for (; j + 4 <= nb; j += 4) {                                        \
            int   s0 = __shfl(idx, j + 0), s1 = __shfl(idx, j + 1);          \
            int   s2 = __shfl(idx, j + 2), s3 = __shfl(idx, j + 3);          \
            float d0 = __shfl(ds, j + 0),  d1 = __shfl(ds, j + 1);           \
            float d2 = __shfl(ds, j + 2),  d3 = __shfl(ds, j + 3);           \
            float g0 = M[(size_t)s0 * 64 + lane];                            \
            float g1 = M[(size_t)s1 * 64 + lane];                            \
            float g2 = M[(size_t)s2 * 64 + lane];                            \
            float g3 = M[(size_t)s3 * 64 + lane];                            \
            a0 = fmaf(d0, g0, a0); a1 = fmaf(d1, g1, a1);                    \
            a2 = fmaf(d2, g2, a2); a3 = fmaf(d3, g3, a3);                    \
        }                                                                    \
        for (; j < nb; ++j) {                                                \
            int s = __shfl(idx, j); float d = __shfl(ds, j);                 \
            a0 = fmaf(d, M[(size_t)s * 64 + lane], a0);                      \
        }                                                                    \
    }

// ------- layer 1 (algebraic fusion):  Y = (relu(agg(X)@W1 + b1)) @ W2 -------
// agg(X@W1) == agg(X)@W1: gather raw X (same indices/table size), apply both
// 64x64 matmuls in the epilogue. No standalone gemm, no xw round-trip.

__global__ void __launch_bounds__(256, 4)
agg_layer1_kernel(const float* __restrict__ X, const int* __restrict__ csr,
                  const float* __restrict__ csrw,
                  const int* __restrict__ rowptr, const int* __restrict__ counts,
                  const float* __restrict__ dinv, const float* __restrict__ W1,
                  const float* __restrict__ b1, const float* __restrict__ W2,
                  float* __restrict__ Y, int N) {
    __shared__ float W1l[64 * 64];
    __shared__ float W2l[64 * 64];
    int tid = threadIdx.x;
    for (int i = tid; i < 4096; i += 256) { W1l[i] = W1[i]; W2l[i] = W2[i]; }
    __syncthreads();
    int lane = tid & 63, wave = tid >> 6;
    float bb = b1[lane];
    int v0 = blockIdx.x * 4 + wave;
    int stride = gridDim.x * 4;
    for (int v = v0; v < N; v += stride) {
        int start = rowptr[v], cnt = counts[v];
        float dv = dinv[v];
        float a0 = dv * X[(size_t)v * 64 + lane], a1 = 0.f, a2 = 0.f, a3 = 0.f;
        AGG_GATHER4(X, a0, a1, a2, a3)
        float z = dv * ((a0 + a1) + (a2 + a3));   // agg(X) row, lane = feature
        float h = bb;                              // h1 = relu(z @ W1 + b1)
#pragma unroll
        for (int k = 0; k < 64; ++k)
            h = fmaf(__shfl(z, k), W1l[k * 64 + lane], h);
        h = fmaxf(h, 0.f);
        float y = 0.f;                             // Y = h1 @ W2
#pragma unroll
        for (int k = 0; k < 64; ++k)
            y = fmaf(__shfl(h, k), W2l[k * 64 + lane], y);
        Y[(size_t)v * 64 + lane] = y;
    }
}

// ------- layer2 agg fused with MLP head -------

__global__ void __launch_bounds__(256, 4)
agg_head_kernel(const float* __restrict__ Yin, const int* __restrict__ csr,
                const float* __restrict__ csrw,
                const int* __restrict__ rowptr, const int* __restrict__ counts,
                const float* __restrict__ dinv, const float* __restrict__ b2,
                const float* __restrict__ dW1, const float* __restrict__ db1,
                const float* __restrict__ dW2, const float* __restrict__ db2,
                float* __restrict__ out, int N) {
    __shared__ float D1[64 * 64];
    __shared__ float W2l[64 * 16];
    int tid = threadIdx.x;
    for (int i = tid; i < 4096; i += 256) D1[i] = dW1[i];
    for (int i = tid; i < 1024; i += 256) W2l[i] = dW2[i];
    __syncthreads();
    int lane = tid & 63, wave = tid >> 6;
    int c = lane & 15, part = lane >> 4;
    float bbl = b2[lane];
    float bb1 = db1[lane];
    float ob  = db2[c];
    int v0 = blockIdx.x * 4 + wave;
    int stride = gridDim.x * 4;
    for (int v = v0; v < N; v += stride) {
        int start = rowptr[v], cnt = counts[v];
        float dv = dinv[v];
        float a0 = dv * Yin[(size_t)v * 64 + lane], a1 = 0.f, a2 = 0.f, a3 = 0.f;
        AGG_GATHER4(Yin, a0, a1, a2, a3)
        float h2 = fmaxf(fmaf(dv, (a0 + a1) + (a2 + a3), bbl), 0.f);  // relu(agg + b2)
        float a = bb1;
#pragma unroll
        for (int k = 0; k < 64; ++k)
            a = fmaf(__shfl(h2, k), D1[k * 64 + lane], a);
        a = fmaxf(a, 0.f);
        float o = 0.f;
#pragma unroll
        for (int kk = 0; kk < 16; ++kk)
            o = fmaf(__shfl(a, part * 16 + kk), W2l[(part * 16 + kk) * 16 + c], o);
        o += __shfl_xor(o, 16);
        o += __shfl_xor(o, 32);
        if (lane < 16) out[(size_t)v * 16 + lane] = o + ob;
    }
}

// ---------------- launch ----------------

extern "C" void kernel_launch(void* const* d_in, const int* in_sizes, int n_in,
                              void* d_out, int out_size, void* d_ws, size_t ws_size,
                              hipStream_t stream) {
    const float* x   = (const float*)d_in[0];
    const int*   ei  = (const int*)d_in[1];
    const float* W1  = (const float*)d_in[2];
    const float* b1  = (const float*)d_in[3];
    const float* W2  = (const float*)d_in[4];
    const float* b2  = (const float*)d_in[5];
    const float* dW1 = (const float*)d_in[6];
    const float* db1 = (const float*)d_in[7];
    const float* dW2 = (const float*)d_in[8];
    const float* db2 = (const float*)d_in[9];
    float* out = (float*)d_out;

    int N = in_sizes[0] / 64;
    int E = in_sizes[1] / 2;
    const int* src = ei;
    const int* dst = ei + E;

    size_t off = 0;
    auto alloc = [&](size_t bytes) {
        void* p = (char*)d_ws + off;
        off += (bytes + 511) & ~(size_t)511;
        return p;
    };
    int*   counts = (int*)alloc((size_t)N * 4);
    int*   fillc  = (int*)alloc((size_t)N * 4);
    int*   rowptr = (int*)alloc((size_t)N * 4);
    int*   bsums  = (int*)alloc(512 * 4);
    int*   csr    = (int*)alloc((size_t)E * 4);
    float* csrw   = (float*)alloc((size_t)E * 4);
    float* dinv   = (float*)alloc((size_t)N * 4);
    float* yw     = (float*)alloc((size_t)N * 64 * 4);

    hipMemsetAsync(counts, 0, (size_t)N * 4, stream);
    hipMemsetAsync(fillc, 0, (size_t)N * 4, stream);

    int nbN = (N + 255) / 256;
    int nbE = (E + 255) / 256;

    count_kernel<<<nbE, 256, 0, stream>>>(dst, counts, E);
    scan_local<<<nbN, 256, 0, stream>>>(counts, rowptr, bsums, dinv, N);
    scan_bsums<<<1, 512, 0, stream>>>(bsums, nbN);
    scan_add<<<nbN, 256, 0, stream>>>(rowptr, bsums, N);
    fill_kernel<<<nbE, 256, 0, stream>>>(src, dst, rowptr, fillc, dinv, csr, csrw, E);

    agg_layer1_kernel<<<2048, 256, 0, stream>>>(x, csr, csrw, rowptr, counts, dinv,
                                                W1, b1, W2, yw, N);
    agg_head_kernel<<<2048, 256, 0, stream>>>(yw, csr, csrw, rowptr, counts, dinv, b2,
                                              dW1, db1, dW2, db2, out, N);
}